// Round 9
// baseline (317.754 us; speedup 1.0000x reference)
//
#include <hip/hip_runtime.h>
#include <math.h>

typedef __attribute__((ext_vector_type(8))) short short8;
typedef __attribute__((ext_vector_type(8))) unsigned short u16x8;
typedef __attribute__((ext_vector_type(4))) float f32x4;

#define EPS_ 1e-5f

__device__ inline unsigned int cvtpk(float a, float b) {
    unsigned int r;
    asm("v_cvt_pk_bf16_f32 %0, %1, %2" : "=v"(r) : "v"(a), "v"(b));
    return r;
}

__device__ inline f32x4 mfma16(u16x8 a, u16x8 b, f32x4 c) {
    return __builtin_amdgcn_mfma_f32_16x16x32_bf16((short8)a, (short8)b, c, 0, 0, 0);
}

__device__ inline void gll16(const unsigned short* g, unsigned short* l) {
    __builtin_amdgcn_global_load_lds(
        (const __attribute__((address_space(1))) unsigned int*)g,
        (__attribute__((address_space(3))) unsigned int*)l, 16, 0, 0);
}

// ---------------------------------------------------------------------------
// k0s: sxsum[b][c] = sum_hw xlo[b][c][:]   (exact fp32, feeds exact S0)
// ---------------------------------------------------------------------------
__global__ __launch_bounds__(256)
void k0s(const float* __restrict__ xlo, float* __restrict__ sxsum)
{
    __shared__ float sred[256];
    int blk = blockIdx.x;
    int cgrp = blk & 15, b = blk >> 4;
    int tid = threadIdx.x;
    int cl = tid >> 3, seg = tid & 7;
    int c = cgrp * 32 + cl;
    const float* row = xlo + ((size_t)b * 512 + c) * 1024 + seg * 128;
    float s = 0.f;
#pragma unroll
    for (int i = 0; i < 32; i++) {
        float4 v = ((const float4*)row)[i];
        s += v.x + v.y + v.z + v.w;
    }
    sred[tid] = s;
    __syncthreads();
    if (seg == 0) {
        float t = 0.f;
#pragma unroll
        for (int e = 0; e < 8; e++) t += sred[cl * 8 + e];
        sxsum[(size_t)b * 512 + c] = t;
    }
}

// ---------------------------------------------------------------------------
// k0w_t: Wt fp32 -> bf16, chunk-tiled + pre-swizzled for linear gll staging.
// ---------------------------------------------------------------------------
__global__ __launch_bounds__(256)
void k0w_t(const float* __restrict__ Wt, unsigned short* __restrict__ wtb)
{
    int blk = blockIdx.x, tid = threadIdx.x;
    int kc = blk >> 3, sub = blk & 7;
    int idx = sub * 256 + tid;
    int row = idx >> 3, s = idx & 7;
    int colbase = kc * 64 + ((s ^ (row & 7)) << 3);
    const float* sp = Wt + (size_t)row * 512 + colbase;
    float4 v0 = ((const float4*)sp)[0];
    float4 v1 = ((const float4*)sp)[1];
    uint4 q = { cvtpk(v0.x, v0.y), cvtpk(v0.z, v0.w),
                cvtpk(v1.x, v1.y), cvtpk(v1.z, v1.w) };
    *(uint4*)&wtb[(size_t)(kc * 2048 + idx) * 8] = q;
}

// ---------------------------------------------------------------------------
// k1: MFMA p/g projections -> S1,S2 partials (frozen).
// ---------------------------------------------------------------------------
#define K1_BODY(C0, VCUR, VNXT, DOPREF)                                          \
  {                                                                              \
    if (DOPREF) {                                                                \
        const float* xc = xlo + ((size_t)b * 512 + (C0) + 64 + cs * 8) * 1024 + hw0 + xrow; \
        _Pragma("unroll")                                                        \
        for (int j = 0; j < 8; j++) VNXT[j] = xc[(size_t)j * 1024];              \
    }                                                                            \
    __syncthreads();                                                             \
    _Pragma("unroll")                                                            \
    for (int k = 0; k < 4; k++) {                                                \
        int idx = k * 256 + tid;                                                 \
        int row = idx >> 3, s = idx & 7;                                         \
        const float* pp = Wp + (size_t)(pbase + row) * 512 + (C0) + s * 8;       \
        const float* pg = Wg + (size_t)(pbase + row) * 512 + (C0) + s * 8;       \
        float4 a0 = ((const float4*)pp)[0], a1 = ((const float4*)pp)[1];         \
        float4 b0 = ((const float4*)pg)[0], b1 = ((const float4*)pg)[1];         \
        uint4 qp = { cvtpk(a0.x,a0.y), cvtpk(a0.z,a0.w),                         \
                     cvtpk(a1.x,a1.y), cvtpk(a1.z,a1.w) };                       \
        uint4 qg = { cvtpk(b0.x,b0.y), cvtpk(b0.z,b0.w),                         \
                     cvtpk(b1.x,b1.y), cvtpk(b1.z,b1.w) };                       \
        int off = row * 64 + ((s ^ (row & 7)) << 3);                             \
        *(uint4*)&sWp[off] = qp;                                                 \
        *(uint4*)&sWg[off] = qg;                                                 \
    }                                                                            \
    {                                                                            \
        uint4 q = { cvtpk(VCUR[0],VCUR[1]), cvtpk(VCUR[2],VCUR[3]),              \
                    cvtpk(VCUR[4],VCUR[5]), cvtpk(VCUR[6],VCUR[7]) };            \
        int phys = cs ^ (xrow & 7);                                              \
        *(uint4*)&sX1[xrow * 64 + phys * 8] = q;                                 \
    }                                                                            \
    __syncthreads();                                                             \
    _Pragma("unroll")                                                            \
    for (int kk = 0; kk < 2; kk++) {                                             \
        u16x8 bf[2];                                                             \
        _Pragma("unroll")                                                        \
        for (int ht = 0; ht < 2; ht++) {                                         \
            int row = ht * 16 + l15;                                             \
            bf[ht] = *(const u16x8*)&sX1[row * 64 + (((kk*4+l4) ^ (row&7)) << 3)]; \
        }                                                                        \
        _Pragma("unroll")                                                        \
        for (int i = 0; i < 2; i++) {                                            \
            int row = w * 32 + i * 16 + l15;                                     \
            int off = row * 64 + (((kk*4+l4) ^ (row&7)) << 3);                   \
            u16x8 ap = *(const u16x8*)&sWp[off];                                 \
            u16x8 ag = *(const u16x8*)&sWg[off];                                 \
            _Pragma("unroll")                                                    \
            for (int ht = 0; ht < 2; ht++) {                                     \
                pacc[i][ht] = mfma16(ap, bf[ht], pacc[i][ht]);                   \
                gacc[i][ht] = mfma16(ag, bf[ht], gacc[i][ht]);                   \
            }                                                                    \
        }                                                                        \
    }                                                                            \
  }

__global__ __launch_bounds__(256, 4)
void k1_att(const float* __restrict__ xlo, const float* __restrict__ Wp,
            const float* __restrict__ Wg, float* __restrict__ att_part)
{
    __shared__ unsigned short sWp[8192];
    __shared__ unsigned short sWg[8192];
    __shared__ unsigned short sX1[2048];

    int tid = threadIdx.x;
    int w = tid >> 6, lane = tid & 63;
    int l15 = lane & 15, l4 = lane >> 4;
    int beta = blockIdx.x;
    int tile = beta & 31, mh = (beta >> 5) & 1, b = beta >> 6;
    int hw0 = tile * 32;
    int pbase = mh * 128;
    int xrow = tid & 31, cs = tid >> 5;

    f32x4 pacc[2][2] = {};
    f32x4 gacc[2][2] = {};

    float vbA[8], vbB[8];
    {
        const float* xc = xlo + ((size_t)b * 512 + cs * 8) * 1024 + hw0 + xrow;
#pragma unroll
        for (int j = 0; j < 8; j++) vbA[j] = xc[(size_t)j * 1024];
    }

    for (int kc2 = 0; kc2 < 4; kc2++) {
        int c0 = kc2 * 128;
        K1_BODY(c0,      vbA, vbB, true);
        K1_BODY(c0 + 64, vbB, vbA, (kc2 < 3));
    }

    float s1 = 0.f, s2 = 0.f;
#pragma unroll
    for (int i = 0; i < 2; i++)
#pragma unroll
        for (int ht = 0; ht < 2; ht++)
#pragma unroll
            for (int r = 0; r < 4; r++) {
                float pv = pacc[i][ht][r], gv = gacc[i][ht][r];
                s1 += pv * gv; s2 += pv * pv * gv;
            }
#pragma unroll
    for (int m = 1; m < 64; m <<= 1) {
        s1 += __shfl_xor(s1, m);
        s2 += __shfl_xor(s2, m);
    }
    if (lane == 0) {
        int g = mh * 4 + w;
        float* dst = att_part + ((size_t)(b * 8 + g) * 32 + tile) * 2;
        dst[0] = s1; dst[1] = s2;
    }
}

// ---------------------------------------------------------------------------
// k1b: one wave per (b,g). Exact fp32 S0 via colsum(Wg)·hwsum(xlo).
// ---------------------------------------------------------------------------
__global__ __launch_bounds__(64)
void k1b_coef(const float* __restrict__ Wg, const float* __restrict__ sxsum,
              const float* __restrict__ att_part, float* __restrict__ coef,
              float a0s, float a1s, float a2s)
{
    int bg = blockIdx.x;
    int b = bg >> 3, g = bg & 7;
    int l = threadIdx.x;
    float s0 = 0.f;
    for (int cc = 0; cc < 512; cc += 64) {
        int c = cc + l;
        float cs = 0.f;
#pragma unroll
        for (int pp = 0; pp < 32; pp++) cs += Wg[(size_t)(g * 32 + pp) * 512 + c];
        s0 += cs * sxsum[(size_t)b * 512 + c];
    }
    float s1 = (l < 32) ? att_part[((size_t)bg * 32 + l) * 2 + 0] : 0.f;
    float s2 = (l < 32) ? att_part[((size_t)bg * 32 + l) * 2 + 1] : 0.f;
#pragma unroll
    for (int m = 1; m < 64; m <<= 1) {
        s0 += __shfl_xor(s0, m);
        s1 += __shfl_xor(s1, m);
        s2 += __shfl_xor(s2, m);
    }
    if (l == 0) {
        coef[bg * 3 + 0] = a0s * s0;
        coef[bg * 3 + 1] = a1s * s1;
        coef[bg * 3 + 2] = a2s * s2;
    }
}

// ===========================================================================
// k2 template: MODE 0 = real, 1 = no-z-store (stats only), 2 = X from
// L2-resident window (isolates X-HBM cost). 2-deep X prefetch (vA/vB/vC),
// pinned issue order [ds_write X | gll Wt | prefetch X+2], counted vmcnt.
// ===========================================================================
#define XLOAD(DST, KC)                                                           \
  { const float* xc = (MODE == 2)                                                \
      ? (xhi + ((size_t)((((KC) & 1) * 64) + w * 8)) * 4096 + hw0 + xrow)        \
      : (xhi + ((size_t)(b * 512 + (KC) * 64 + w * 8)) * 4096 + hw0 + xrow);     \
    _Pragma("unroll")                                                            \
    for (int j = 0; j < 8; j++) DST[j] = xc[(size_t)j * 4096]; }

#define K2CHUNK(KC, WBUF, PBUF, DOPREF, VMC)                                     \
  {                                                                              \
    asm volatile("s_waitcnt lgkmcnt(0)" ::: "memory");                           \
    __builtin_amdgcn_s_barrier();                                                \
    __builtin_amdgcn_sched_barrier(0);                                           \
    {   /* X_k regs -> bf16 -> swizzled ds_write */                              \
        uint4 q = { cvtpk(WBUF[0],WBUF[1]), cvtpk(WBUF[2],WBUF[3]),              \
                    cvtpk(WBUF[4],WBUF[5]), cvtpk(WBUF[6],WBUF[7]) };            \
        int phys = w ^ (xrow & 7);                                               \
        *(uint4*)&sX[xrow * 64 + phys * 8] = q;                                  \
    }                                                                            \
    __builtin_amdgcn_sched_barrier(0);                                           \
    _Pragma("unroll")                                                            \
    for (int k = 0; k < 4; k++) {                                                \
        int u = k * 512 + tid;                                                   \
        gll16(wtb + (((size_t)(KC) * 2048 + u) << 3), &sMain[u << 3]);           \
    }                                                                            \
    __builtin_amdgcn_sched_barrier(0);                                           \
    if (DOPREF) { XLOAD(PBUF, (KC) + 2) }                                        \
    asm volatile("s_waitcnt vmcnt(" #VMC ") lgkmcnt(0)" ::: "memory");           \
    __builtin_amdgcn_s_barrier();                                                \
    __builtin_amdgcn_sched_barrier(0);                                           \
    _Pragma("unroll")                                                            \
    for (int kk = 0; kk < 2; kk++) {                                             \
        u16x8 bf[4];                                                             \
        _Pragma("unroll")                                                        \
        for (int ht = 0; ht < 4; ht++) {                                         \
            int row = ht * 16 + l15;                                             \
            bf[ht] = *(const u16x8*)&sX[row * 64 + (((kk*4+l4) ^ (row&7)) << 3)]; \
        }                                                                        \
        _Pragma("unroll")                                                        \
        for (int i = 0; i < 2; i++) {                                            \
            int row = w * 32 + i * 16 + l15;                                     \
            u16x8 af = *(const u16x8*)&sMain[row * 64 + (((kk*4+l4) ^ (row&7)) << 3)]; \
            _Pragma("unroll")                                                    \
            for (int ht = 0; ht < 4; ht++)                                       \
                acc[i][ht] = mfma16(af, bf[ht], acc[i][ht]);                     \
        }                                                                        \
    }                                                                            \
  }

template<int MODE>
__global__ __launch_bounds__(512, 4)
void k2t(const float* __restrict__ xhi, const unsigned short* __restrict__ wtb,
         const float* __restrict__ Wz, const float* __restrict__ coef,
         float* __restrict__ zout, float* __restrict__ zstat)
{
    __shared__ unsigned short sMain[16384];  // 32 KB: Wt chunk, then xx[64hw][256p]
    __shared__ unsigned short sX[4096];      // 8 KB: X tile; epilogue: float sR[512]

    int tid = threadIdx.x;
    int w = tid >> 6, lane = tid & 63;
    int l15 = lane & 15, l4 = lane >> 4;
    int hwt = blockIdx.x & 63, b = blockIdx.x >> 6;
    int hw0 = hwt * 64;
    int xrow = tid & 63;

    const float* cf = coef + (size_t)(b * 8 + w) * 3;
    float c0v = cf[0], c1v = cf[1], c2v = cf[2];

    f32x4 acc[2][4] = {};

    float vA[8], vB[8], vC[8];
    XLOAD(vA, 0)
    XLOAD(vB, 1)

    K2CHUNK(0, vA, vC, 1, 8)
    K2CHUNK(1, vB, vA, 1, 8)
    K2CHUNK(2, vC, vB, 1, 8)
    K2CHUNK(3, vA, vC, 1, 8)
    K2CHUNK(4, vB, vA, 1, 8)
    K2CHUNK(5, vC, vB, 1, 8)
    K2CHUNK(6, vA, vC, 0, 0)
    K2CHUNK(7, vB, vA, 0, 0)

    // poly: xx = c1*t + c2*t^2
#pragma unroll
    for (int i = 0; i < 2; i++)
#pragma unroll
        for (int ht = 0; ht < 4; ht++) {
            f32x4 t = acc[i][ht];
            acc[i][ht] = c1v * t + c2v * t * t;
        }
    __syncthreads();   // reuse sMain as xx, sX as sR

    // xx -> sMain as [64 hw][256 p] bf16; wave granules [4w,4w+4), swz ^(row&3)
#pragma unroll
    for (int i = 0; i < 2; i++)
#pragma unroll
        for (int ht = 0; ht < 4; ht++) {
            int row = ht * 16 + l15;
            f32x4 xv = acc[i][ht];
            uint2 q = { cvtpk(xv[0], xv[1]), cvtpk(xv[2], xv[3]) };
            int phys = w * 4 + ((i * 2 + (l4 >> 1)) ^ (row & 3));
            *(uint2*)&sMain[row * 256 + phys * 8 + (l4 & 1) * 4] = q;
        }

    float* sR = (float*)sX;
    {
        const float* wr = Wz + (size_t)tid * 32;
        float s = 0.f;
#pragma unroll
        for (int q = 0; q < 8; q++) {
            float4 v = ((const float4*)wr)[q];
            s += v.x + v.y + v.z + v.w;
        }
        sR[tid] = s;
    }
    u16x8 wzf[4];
#pragma unroll
    for (int ot = 0; ot < 4; ot++) {
        const float* wr = Wz + (size_t)(w * 64 + ot * 16 + l15) * 32 + l4 * 8;
        float4 v0 = ((const float4*)wr)[0];
        float4 v1 = ((const float4*)wr)[1];
        uint4 q = { cvtpk(v0.x,v0.y), cvtpk(v0.z,v0.w),
                    cvtpk(v1.x,v1.y), cvtpk(v1.z,v1.w) };
        wzf[ot] = *(u16x8*)&q;
    }
    __syncthreads();

    float s = 0.f, s2a = 0.f;
    f32x4 zero4 = {0.f, 0.f, 0.f, 0.f};
#pragma unroll
    for (int ht = 0; ht < 4; ht++) {
        int row = ht * 16 + l15;
        u16x8 bfr = *(const u16x8*)&sMain[row * 256 + (w * 4 + (l4 ^ (row & 3))) * 8];
#pragma unroll
        for (int ot = 0; ot < 4; ot++) {
            f32x4 z = mfma16(wzf[ot], bfr, zero4);
            f32x4 rv = *(const f32x4*)&sR[w * 64 + ot * 16 + l4 * 4];
            z = z + c0v * rv;
            float* zp = zout + ((size_t)(b * 512 + w * 64 + ot * 16 + l4 * 4)) * 4096
                      + hw0 + ht * 16 + l15;
#pragma unroll
            for (int r = 0; r < 4; r++) {
                if (MODE != 1) zp[(size_t)r * 4096] = z[r];
                s += z[r]; s2a += z[r] * z[r];
            }
        }
    }
#pragma unroll
    for (int m = 1; m < 64; m <<= 1) {
        s   += __shfl_xor(s, m);
        s2a += __shfl_xor(s2a, m);
    }
    if (lane == 0) {
        atomicAdd(&zstat[(size_t)(b * 8 + w) * 2 + 0], s);
        atomicAdd(&zstat[(size_t)(b * 8 + w) * 2 + 1], s2a);
    }
}

// ---------------------------------------------------------------------------
// k2 fallback (fp32 Wt staging) when ws too small for wtb.
// ---------------------------------------------------------------------------
#define K2_BODY(C0, VCUR, VNXT, DOPREF)                                          \
  {                                                                              \
    if (DOPREF) {                                                                \
        const float* xc = xhi + ((size_t)b * 512 + (C0) + 64 + w * 8) * 4096 + hw0 + xrow; \
        _Pragma("unroll")                                                        \
        for (int j = 0; j < 8; j++) VNXT[j] = xc[(size_t)j * 4096];              \
    }                                                                            \
    __syncthreads();                                                             \
    _Pragma("unroll")                                                            \
    for (int k = 0; k < 4; k++) {                                                \
        int idx = k * 512 + tid;                                                 \
        int row = idx >> 3, s = idx & 7;                                         \
        const float* sp = Wt + (size_t)row * 512 + (C0) + s * 8;                 \
        float4 v0 = ((const float4*)sp)[0];                                      \
        float4 v1 = ((const float4*)sp)[1];                                      \
        uint4 q = { cvtpk(v0.x,v0.y), cvtpk(v0.z,v0.w),                          \
                    cvtpk(v1.x,v1.y), cvtpk(v1.z,v1.w) };                        \
        *(uint4*)&sMain[row * 64 + ((s ^ (row & 7)) << 3)] = q;                  \
    }                                                                            \
    {                                                                            \
        uint4 q = { cvtpk(VCUR[0],VCUR[1]), cvtpk(VCUR[2],VCUR[3]),              \
                    cvtpk(VCUR[4],VCUR[5]), cvtpk(VCUR[6],VCUR[7]) };            \
        int phys = w ^ (xrow & 7);                                               \
        *(uint4*)&sX[xrow * 64 + phys * 8] = q;                                  \
    }                                                                            \
    __syncthreads();                                                             \
    _Pragma("unroll")                                                            \
    for (int kk = 0; kk < 2; kk++) {                                             \
        u16x8 bf[4];                                                             \
        _Pragma("unroll")                                                        \
        for (int ht = 0; ht < 4; ht++) {                                         \
            int row = ht * 16 + l15;                                             \
            bf[ht] = *(const u16x8*)&sX[row * 64 + (((kk*4+l4) ^ (row&7)) << 3)]; \
        }                                                                        \
        _Pragma("unroll")                                                        \
        for (int i = 0; i < 2; i++) {                                            \
            int row = w * 32 + i * 16 + l15;                                     \
            u16x8 af = *(const u16x8*)&sMain[row * 64 + (((kk*4+l4) ^ (row&7)) << 3)]; \
            _Pragma("unroll")                                                    \
            for (int ht = 0; ht < 4; ht++)                                       \
                acc[i][ht] = mfma16(af, bf[ht], acc[i][ht]);                     \
        }                                                                        \
    }                                                                            \
  }

__global__ __launch_bounds__(512, 4)
void k2_main_fb(const float* __restrict__ xhi, const float* __restrict__ Wt,
                const float* __restrict__ Wz, const float* __restrict__ coef,
                float* __restrict__ zout, float* __restrict__ zstat)
{
    __shared__ unsigned short sMain[16384];
    __shared__ unsigned short sX[4096];

    int tid = threadIdx.x;
    int w = tid >> 6, lane = tid & 63;
    int l15 = lane & 15, l4 = lane >> 4;
    int hwt = blockIdx.x & 63, b = blockIdx.x >> 6;
    int hw0 = hwt * 64;
    int xrow = tid & 63;

    const float* cf = coef + (size_t)(b * 8 + w) * 3;
    float c0v = cf[0], c1v = cf[1], c2v = cf[2];

    f32x4 acc[2][4] = {};

    float vbA[8], vbB[8];
    {
        const float* xc = xhi + ((size_t)b * 512 + w * 8) * 4096 + hw0 + xrow;
#pragma unroll
        for (int j = 0; j < 8; j++) vbA[j] = xc[(size_t)j * 4096];
    }

    for (int kc2 = 0; kc2 < 4; kc2++) {
        int c0 = kc2 * 128;
        K2_BODY(c0,      vbA, vbB, true);
        K2_BODY(c0 + 64, vbB, vbA, (kc2 < 3));
    }

#pragma unroll
    for (int i = 0; i < 2; i++)
#pragma unroll
        for (int ht = 0; ht < 4; ht++) {
            f32x4 t = acc[i][ht];
            acc[i][ht] = c1v * t + c2v * t * t;
        }
    __syncthreads();
#pragma unroll
    for (int i = 0; i < 2; i++)
#pragma unroll
        for (int ht = 0; ht < 4; ht++) {
            int row = ht * 16 + l15;
            f32x4 xv = acc[i][ht];
            uint2 q = { cvtpk(xv[0], xv[1]), cvtpk(xv[2], xv[3]) };
            int phys = w * 4 + ((i * 2 + (l4 >> 1)) ^ (row & 3));
            *(uint2*)&sMain[row * 256 + phys * 8 + (l4 & 1) * 4] = q;
        }
    float* sR = (float*)sX;
    {
        const float* wr = Wz + (size_t)tid * 32;
        float s = 0.f;
#pragma unroll
        for (int q = 0; q < 8; q++) {
            float4 v = ((const float4*)wr)[q];
            s += v.x + v.y + v.z + v.w;
        }
        sR[tid] = s;
    }
    u16x8 wzf[4];
#pragma unroll
    for (int ot = 0; ot < 4; ot++) {
        const float* wr = Wz + (size_t)(w * 64 + ot * 16 + l15) * 32 + l4 * 8;
        float4 v0 = ((const float4*)wr)[0];
        float4 v1 = ((const float4*)wr)[1];
        uint4 q = { cvtpk(v0.x,v0.y), cvtpk(v0.z,v0.w),
                    cvtpk(v1.x,v1.y), cvtpk(v1.z,v1.w) };
        wzf[ot] = *(u16x8*)&q;
    }
    __syncthreads();

    float s = 0.f, s2a = 0.f;
    f32x4 zero4 = {0.f, 0.f, 0.f, 0.f};
#pragma unroll
    for (int ht = 0; ht < 4; ht++) {
        int row = ht * 16 + l15;
        u16x8 bfr = *(const u16x8*)&sMain[row * 256 + (w * 4 + (l4 ^ (row & 3))) * 8];
#pragma unroll
        for (int ot = 0; ot < 4; ot++) {
            f32x4 z = mfma16(wzf[ot], bfr, zero4);
            f32x4 rv = *(const f32x4*)&sR[w * 64 + ot * 16 + l4 * 4];
            z = z + c0v * rv;
            float* zp = zout + ((size_t)(b * 512 + w * 64 + ot * 16 + l4 * 4)) * 4096
                      + hw0 + ht * 16 + l15;
#pragma unroll
            for (int r = 0; r < 4; r++) {
                zp[(size_t)r * 4096] = z[r];
                s += z[r]; s2a += z[r] * z[r];
            }
        }
    }
#pragma unroll
    for (int m = 1; m < 64; m <<= 1) {
        s   += __shfl_xor(s, m);
        s2a += __shfl_xor(s2a, m);
    }
    if (lane == 0) {
        atomicAdd(&zstat[(size_t)(b * 8 + w) * 2 + 0], s);
        atomicAdd(&zstat[(size_t)(b * 8 + w) * 2 + 1], s2a);
    }
}

__global__ void k2b_gn(const float* __restrict__ zstat, float* __restrict__ gnstat)
{
    int t = threadIdx.x;
    if (t >= 128) return;
    float S = zstat[t * 2], S2 = zstat[t * 2 + 1];
    const float N = 64.0f * 4096.0f;
    float mean = S / N;
    float var = S2 / N - mean * mean;
    var = var < 0.f ? 0.f : var;
    gnstat[t * 2] = mean;
    gnstat[t * 2 + 1] = rsqrtf(var + EPS_);
}

// ---------------------------------------------------------------------------
// k3: out = (z - mean)*rsig*gn_w + gn_b + input_high  (in place on d_out)
// ---------------------------------------------------------------------------
__global__ __launch_bounds__(256)
void k3_final(float* __restrict__ out, const float* __restrict__ xhi,
              const float* __restrict__ gnstat, const float* __restrict__ gnw,
              const float* __restrict__ gnb)
{
#pragma unroll
    for (int k = 0; k < 4; k++) {
        size_t idx = (size_t)blockIdx.x * 1024 + (size_t)k * 256 + threadIdx.x;
        size_t e = idx * 4;
        int ch = (int)((e >> 12) & 511);
        int b  = (int)(e >> 21);
        int gg = ch >> 6;
        const float* gs = gnstat + (size_t)(b * 8 + gg) * 2;
        float mean = gs[0];
        float w = gnw[ch] * gs[1];
        float bb = gnb[ch];
        float4 z = ((const float4*)out)[idx];
        float4 xv = ((const float4*)xhi)[idx];
        float4 r;
        r.x = (z.x - mean) * w + bb + xv.x;
        r.y = (z.y - mean) * w + bb + xv.y;
        r.z = (z.z - mean) * w + bb + xv.z;
        r.w = (z.w - mean) * w + bb + xv.w;
        ((float4*)out)[idx] = r;
    }
}

extern "C" void kernel_launch(void* const* d_in, const int* in_sizes, int n_in,
                              void* d_out, int out_size, void* d_ws, size_t ws_size,
                              hipStream_t stream) {
    (void)in_sizes; (void)n_in; (void)out_size;
    const float* xhi = (const float*)d_in[0];
    const float* xlo = (const float*)d_in[1];
    const float* Wt  = (const float*)d_in[2];
    const float* Wp  = (const float*)d_in[3];
    const float* Wg  = (const float*)d_in[4];
    const float* Wz  = (const float*)d_in[5];
    const float* gnw = (const float*)d_in[6];
    const float* gnb = (const float*)d_in[7];
    float* out = (float*)d_out;
    float* ws  = (float*)d_ws;

    float* sxsum    = ws;              // 8192 floats
    float* att_part = ws + 8192;       // 8192 (reused as ablation zstat scratch)
    float* coef     = ws + 16384;      // 384
    float* zstat    = ws + 16768;      // 256
    float* gnstat   = ws + 17024;      // 256   -> 17280 f = 69120 B
    unsigned short* wtb = (unsigned short*)((char*)d_ws + 69632);  // 262144 B
    float* zstat_abl = att_part;       // dead after k1b; ablation stats sink

    const size_t WS_NEED = 69632 + 262144;   // 331776
    bool use_gll = (ws_size >= WS_NEED);

    double g2 = 2.0e-4;
    double ee = exp(-g2);
    float a0s = (float)ee;
    float a1s = (float)(g2 * ee);
    float a2s = (float)(g2 * g2 * 0.5 * ee);

    k0s     <<<dim3(256),  dim3(256), 0, stream>>>(xlo, sxsum);
    k1_att  <<<dim3(1024), dim3(256), 0, stream>>>(xlo, Wp, Wg, att_part);
    k1b_coef<<<dim3(128),  dim3(64),  0, stream>>>(Wg, sxsum, att_part, coef, a0s, a1s, a2s);
    hipMemsetAsync(zstat, 0, 256 * sizeof(float), stream);
    if (use_gll) {
        k0w_t  <<<dim3(64),   dim3(256), 0, stream>>>(Wt, wtb);
        // diagnostic ablations (half grid, b 0..7; d_out fully overwritten after)
        k2t<1> <<<dim3(512),  dim3(512), 0, stream>>>(xhi, wtb, Wz, coef, out, zstat_abl);
        k2t<2> <<<dim3(512),  dim3(512), 0, stream>>>(xhi, wtb, Wz, coef, out, zstat_abl);
        // real k2
        k2t<0> <<<dim3(1024), dim3(512), 0, stream>>>(xhi, wtb, Wz, coef, out, zstat);
    } else {
        k2_main_fb<<<dim3(1024), dim3(512), 0, stream>>>(xhi, Wt, Wz, coef, out, zstat);
    }
    k2b_gn  <<<dim3(1),    dim3(128), 0, stream>>>(zstat, gnstat);
    k3_final<<<dim3(8192), dim3(256), 0, stream>>>(out, xhi, gnstat, gnw, gnb);
}

// Round 10
// 207.852 us; speedup vs baseline: 1.5287x; 1.5287x over previous
//
#include <hip/hip_runtime.h>
#include <math.h>

typedef __attribute__((ext_vector_type(8))) short short8;
typedef __attribute__((ext_vector_type(8))) unsigned short u16x8;
typedef __attribute__((ext_vector_type(4))) float f32x4;

#define EPS_ 1e-5f

__device__ inline unsigned int cvtpk(float a, float b) {
    unsigned int r;
    asm("v_cvt_pk_bf16_f32 %0, %1, %2" : "=v"(r) : "v"(a), "v"(b));
    return r;
}

__device__ inline f32x4 mfma16(u16x8 a, u16x8 b, f32x4 c) {
    return __builtin_amdgcn_mfma_f32_16x16x32_bf16((short8)a, (short8)b, c, 0, 0, 0);
}

__device__ inline void gll16(const unsigned short* g, unsigned short* l) {
    __builtin_amdgcn_global_load_lds(
        (const __attribute__((address_space(1))) unsigned int*)g,
        (__attribute__((address_space(3))) unsigned int*)l, 16, 0, 0);
}

// ---------------------------------------------------------------------------
// k0s: sxsum[b][c] = sum_hw xlo[b][c][:]   (exact fp32, feeds exact S0)
// ---------------------------------------------------------------------------
__global__ __launch_bounds__(256)
void k0s(const float* __restrict__ xlo, float* __restrict__ sxsum)
{
    __shared__ float sred[256];
    int blk = blockIdx.x;
    int cgrp = blk & 15, b = blk >> 4;
    int tid = threadIdx.x;
    int cl = tid >> 3, seg = tid & 7;
    int c = cgrp * 32 + cl;
    const float* row = xlo + ((size_t)b * 512 + c) * 1024 + seg * 128;
    float s = 0.f;
#pragma unroll
    for (int i = 0; i < 32; i++) {
        float4 v = ((const float4*)row)[i];
        s += v.x + v.y + v.z + v.w;
    }
    sred[tid] = s;
    __syncthreads();
    if (seg == 0) {
        float t = 0.f;
#pragma unroll
        for (int e = 0; e < 8; e++) t += sred[cl * 8 + e];
        sxsum[(size_t)b * 512 + c] = t;
    }
}

// ---------------------------------------------------------------------------
// k0w_t: Wt fp32 -> bf16, chunk-tiled + pre-swizzled for linear gll staging.
// ---------------------------------------------------------------------------
__global__ __launch_bounds__(256)
void k0w_t(const float* __restrict__ Wt, unsigned short* __restrict__ wtb)
{
    int blk = blockIdx.x, tid = threadIdx.x;
    int kc = blk >> 3, sub = blk & 7;
    int idx = sub * 256 + tid;
    int row = idx >> 3, s = idx & 7;
    int colbase = kc * 64 + ((s ^ (row & 7)) << 3);
    const float* sp = Wt + (size_t)row * 512 + colbase;
    float4 v0 = ((const float4*)sp)[0];
    float4 v1 = ((const float4*)sp)[1];
    uint4 q = { cvtpk(v0.x, v0.y), cvtpk(v0.z, v0.w),
                cvtpk(v1.x, v1.y), cvtpk(v1.z, v1.w) };
    *(uint4*)&wtb[(size_t)(kc * 2048 + idx) * 8] = q;
}

// ---------------------------------------------------------------------------
// k1: MFMA p/g projections -> S1,S2 partials (frozen).
// ---------------------------------------------------------------------------
#define K1_BODY(C0, VCUR, VNXT, DOPREF)                                          \
  {                                                                              \
    if (DOPREF) {                                                                \
        const float* xc = xlo + ((size_t)b * 512 + (C0) + 64 + cs * 8) * 1024 + hw0 + xrow; \
        _Pragma("unroll")                                                        \
        for (int j = 0; j < 8; j++) VNXT[j] = xc[(size_t)j * 1024];              \
    }                                                                            \
    __syncthreads();                                                             \
    _Pragma("unroll")                                                            \
    for (int k = 0; k < 4; k++) {                                                \
        int idx = k * 256 + tid;                                                 \
        int row = idx >> 3, s = idx & 7;                                         \
        const float* pp = Wp + (size_t)(pbase + row) * 512 + (C0) + s * 8;       \
        const float* pg = Wg + (size_t)(pbase + row) * 512 + (C0) + s * 8;       \
        float4 a0 = ((const float4*)pp)[0], a1 = ((const float4*)pp)[1];         \
        float4 b0 = ((const float4*)pg)[0], b1 = ((const float4*)pg)[1];         \
        uint4 qp = { cvtpk(a0.x,a0.y), cvtpk(a0.z,a0.w),                         \
                     cvtpk(a1.x,a1.y), cvtpk(a1.z,a1.w) };                       \
        uint4 qg = { cvtpk(b0.x,b0.y), cvtpk(b0.z,b0.w),                         \
                     cvtpk(b1.x,b1.y), cvtpk(b1.z,b1.w) };                       \
        int off = row * 64 + ((s ^ (row & 7)) << 3);                             \
        *(uint4*)&sWp[off] = qp;                                                 \
        *(uint4*)&sWg[off] = qg;                                                 \
    }                                                                            \
    {                                                                            \
        uint4 q = { cvtpk(VCUR[0],VCUR[1]), cvtpk(VCUR[2],VCUR[3]),              \
                    cvtpk(VCUR[4],VCUR[5]), cvtpk(VCUR[6],VCUR[7]) };            \
        int phys = cs ^ (xrow & 7);                                              \
        *(uint4*)&sX1[xrow * 64 + phys * 8] = q;                                 \
    }                                                                            \
    __syncthreads();                                                             \
    _Pragma("unroll")                                                            \
    for (int kk = 0; kk < 2; kk++) {                                             \
        u16x8 bf[2];                                                             \
        _Pragma("unroll")                                                        \
        for (int ht = 0; ht < 2; ht++) {                                         \
            int row = ht * 16 + l15;                                             \
            bf[ht] = *(const u16x8*)&sX1[row * 64 + (((kk*4+l4) ^ (row&7)) << 3)]; \
        }                                                                        \
        _Pragma("unroll")                                                        \
        for (int i = 0; i < 2; i++) {                                            \
            int row = w * 32 + i * 16 + l15;                                     \
            int off = row * 64 + (((kk*4+l4) ^ (row&7)) << 3);                   \
            u16x8 ap = *(const u16x8*)&sWp[off];                                 \
            u16x8 ag = *(const u16x8*)&sWg[off];                                 \
            _Pragma("unroll")                                                    \
            for (int ht = 0; ht < 2; ht++) {                                     \
                pacc[i][ht] = mfma16(ap, bf[ht], pacc[i][ht]);                   \
                gacc[i][ht] = mfma16(ag, bf[ht], gacc[i][ht]);                   \
            }                                                                    \
        }                                                                        \
    }                                                                            \
  }

__global__ __launch_bounds__(256, 4)
void k1_att(const float* __restrict__ xlo, const float* __restrict__ Wp,
            const float* __restrict__ Wg, float* __restrict__ att_part)
{
    __shared__ unsigned short sWp[8192];
    __shared__ unsigned short sWg[8192];
    __shared__ unsigned short sX1[2048];

    int tid = threadIdx.x;
    int w = tid >> 6, lane = tid & 63;
    int l15 = lane & 15, l4 = lane >> 4;
    int beta = blockIdx.x;
    int tile = beta & 31, mh = (beta >> 5) & 1, b = beta >> 6;
    int hw0 = tile * 32;
    int pbase = mh * 128;
    int xrow = tid & 31, cs = tid >> 5;

    f32x4 pacc[2][2] = {};
    f32x4 gacc[2][2] = {};

    float vbA[8], vbB[8];
    {
        const float* xc = xlo + ((size_t)b * 512 + cs * 8) * 1024 + hw0 + xrow;
#pragma unroll
        for (int j = 0; j < 8; j++) vbA[j] = xc[(size_t)j * 1024];
    }

    for (int kc2 = 0; kc2 < 4; kc2++) {
        int c0 = kc2 * 128;
        K1_BODY(c0,      vbA, vbB, true);
        K1_BODY(c0 + 64, vbB, vbA, (kc2 < 3));
    }

    float s1 = 0.f, s2 = 0.f;
#pragma unroll
    for (int i = 0; i < 2; i++)
#pragma unroll
        for (int ht = 0; ht < 2; ht++)
#pragma unroll
            for (int r = 0; r < 4; r++) {
                float pv = pacc[i][ht][r], gv = gacc[i][ht][r];
                s1 += pv * gv; s2 += pv * pv * gv;
            }
#pragma unroll
    for (int m = 1; m < 64; m <<= 1) {
        s1 += __shfl_xor(s1, m);
        s2 += __shfl_xor(s2, m);
    }
    if (lane == 0) {
        int g = mh * 4 + w;
        float* dst = att_part + ((size_t)(b * 8 + g) * 32 + tile) * 2;
        dst[0] = s1; dst[1] = s2;
    }
}

// ---------------------------------------------------------------------------
// k1b: one wave per (b,g). Exact fp32 S0 via colsum(Wg)·hwsum(xlo).
// ---------------------------------------------------------------------------
__global__ __launch_bounds__(64)
void k1b_coef(const float* __restrict__ Wg, const float* __restrict__ sxsum,
              const float* __restrict__ att_part, float* __restrict__ coef,
              float a0s, float a1s, float a2s)
{
    int bg = blockIdx.x;
    int b = bg >> 3, g = bg & 7;
    int l = threadIdx.x;
    float s0 = 0.f;
    for (int cc = 0; cc < 512; cc += 64) {
        int c = cc + l;
        float cs = 0.f;
#pragma unroll
        for (int pp = 0; pp < 32; pp++) cs += Wg[(size_t)(g * 32 + pp) * 512 + c];
        s0 += cs * sxsum[(size_t)b * 512 + c];
    }
    float s1 = (l < 32) ? att_part[((size_t)bg * 32 + l) * 2 + 0] : 0.f;
    float s2 = (l < 32) ? att_part[((size_t)bg * 32 + l) * 2 + 1] : 0.f;
#pragma unroll
    for (int m = 1; m < 64; m <<= 1) {
        s0 += __shfl_xor(s0, m);
        s1 += __shfl_xor(s1, m);
        s2 += __shfl_xor(s2, m);
    }
    if (l == 0) {
        coef[bg * 3 + 0] = a0s * s0;
        coef[bg * 3 + 1] = a1s * s1;
        coef[bg * 3 + 2] = a2s * s2;
    }
}

// ===========================================================================
// k2: latency-clean pipeline.
// sWt 32KB single-buffered Wt (A-frags pulled to regs before overwrite);
// sX 16KB double-buffered X tile. 2 barriers/chunk, zero naked waits:
//   vmcnt(0) pre-ds_write waits X-pref issued a full chunk earlier;
//   end vmcnt(8) waits gll that had the whole MFMA phase to complete.
// ===========================================================================
#define XLOAD(DST, KC)                                                           \
  { const float* xc = xhi + ((size_t)(b * 512 + (KC) * 64 + w * 8)) * 4096 + hw0 + xrow; \
    _Pragma("unroll")                                                            \
    for (int j = 0; j < 8; j++) DST[j] = xc[(size_t)j * 4096]; }

#define K2NCHUNK(KC, WBUF, PBUF, DOGLL, DOPREF, ENDVMC)                          \
  {                                                                              \
    /* A-fragments (Wt_KC) -> regs, before sWt is overwritten */                 \
    int row0 = w * 32 + l15, row1 = w * 32 + 16 + l15;                           \
    u16x8 af0 = *(const u16x8*)&sWt[row0 * 64 + (((0 + l4) ^ (row0 & 7)) << 3)]; \
    u16x8 af1 = *(const u16x8*)&sWt[row1 * 64 + (((0 + l4) ^ (row1 & 7)) << 3)]; \
    u16x8 af2 = *(const u16x8*)&sWt[row0 * 64 + (((4 + l4) ^ (row0 & 7)) << 3)]; \
    u16x8 af3 = *(const u16x8*)&sWt[row1 * 64 + (((4 + l4) ^ (row1 & 7)) << 3)]; \
    /* X_{KC+1}: regs (in flight a full chunk) -> sX[(KC+1)&1] */                \
    asm volatile("s_waitcnt vmcnt(0)" ::: "memory");                             \
    __builtin_amdgcn_sched_barrier(0);                                           \
    {                                                                            \
        uint4 q = { cvtpk(WBUF[0],WBUF[1]), cvtpk(WBUF[2],WBUF[3]),              \
                    cvtpk(WBUF[4],WBUF[5]), cvtpk(WBUF[6],WBUF[7]) };            \
        int phys = w ^ (xrow & 7);                                               \
        *(uint4*)&sX[(((KC)+1)&1) * 4096 + xrow * 64 + phys * 8] = q;            \
    }                                                                            \
    asm volatile("s_waitcnt lgkmcnt(0)" ::: "memory");                           \
    __builtin_amdgcn_s_barrier();                                                \
    __builtin_amdgcn_sched_barrier(0);                                           \
    if (DOGLL) {                                                                 \
        _Pragma("unroll")                                                        \
        for (int k = 0; k < 4; k++) {                                            \
            int u = k * 512 + tid;                                               \
            gll16(wtb + (((size_t)((KC)+1) * 2048 + u) << 3), &sWt[u << 3]);     \
        }                                                                        \
    }                                                                            \
    if (DOPREF) { XLOAD(PBUF, (KC)+2) }                                          \
    __builtin_amdgcn_sched_barrier(0);                                           \
    __builtin_amdgcn_s_setprio(1);                                               \
    _Pragma("unroll")                                                            \
    for (int kk = 0; kk < 2; kk++) {                                             \
        u16x8 bf[4];                                                             \
        _Pragma("unroll")                                                        \
        for (int ht = 0; ht < 4; ht++) {                                         \
            int row = ht * 16 + l15;                                             \
            bf[ht] = *(const u16x8*)&sX[((KC)&1) * 4096 + row * 64 + (((kk*4+l4) ^ (row&7)) << 3)]; \
        }                                                                        \
        _Pragma("unroll")                                                        \
        for (int ht = 0; ht < 4; ht++) {                                         \
            acc[0][ht] = mfma16(kk == 0 ? af0 : af2, bf[ht], acc[0][ht]);        \
            acc[1][ht] = mfma16(kk == 0 ? af1 : af3, bf[ht], acc[1][ht]);        \
        }                                                                        \
    }                                                                            \
    __builtin_amdgcn_s_setprio(0);                                               \
    asm volatile("s_waitcnt vmcnt(" #ENDVMC ")" ::: "memory");                   \
    __builtin_amdgcn_s_barrier();                                                \
    __builtin_amdgcn_sched_barrier(0);                                           \
  }

__global__ __launch_bounds__(512, 4)
void k2_main_g(const float* __restrict__ xhi, const unsigned short* __restrict__ wtb,
               const float* __restrict__ Wz, const float* __restrict__ coef,
               float* __restrict__ zout, float* __restrict__ zstat)
{
    __shared__ unsigned short sWt[16384];   // 32 KB: Wt chunk; epilogue xx[64hw][256p]
    __shared__ unsigned short sX[8192];     // 16 KB: 2 x X tile; epilogue float sR[512]

    int tid = threadIdx.x;
    int w = tid >> 6, lane = tid & 63;
    int l15 = lane & 15, l4 = lane >> 4;
    int hwt = blockIdx.x & 63, b = blockIdx.x >> 6;
    int hw0 = hwt * 64;
    int xrow = tid & 63;

    const float* cf = coef + (size_t)(b * 8 + w) * 3;
    float c0v = cf[0], c1v = cf[1], c2v = cf[2];

    f32x4 acc[2][4] = {};

    float vA[8], vB[8];
    // prologue: gll Wt_0 (oldest), then X0->vA, X1->vB; vmcnt(8) drains gll+X0
    {
#pragma unroll
        for (int k = 0; k < 4; k++) {
            int u = k * 512 + tid;
            gll16(wtb + ((size_t)u << 3), &sWt[u << 3]);
        }
        XLOAD(vA, 0)
        XLOAD(vB, 1)
        asm volatile("s_waitcnt vmcnt(8)" ::: "memory");
        __builtin_amdgcn_s_barrier();
        __builtin_amdgcn_sched_barrier(0);
        uint4 q = { cvtpk(vA[0],vA[1]), cvtpk(vA[2],vA[3]),
                    cvtpk(vA[4],vA[5]), cvtpk(vA[6],vA[7]) };
        int phys = w ^ (xrow & 7);
        *(uint4*)&sX[xrow * 64 + phys * 8] = q;   // X_0 -> sX[0]
    }

    K2NCHUNK(0, vB, vA, 1, 1, 8)
    K2NCHUNK(1, vA, vB, 1, 1, 8)
    K2NCHUNK(2, vB, vA, 1, 1, 8)
    K2NCHUNK(3, vA, vB, 1, 1, 8)
    K2NCHUNK(4, vB, vA, 1, 1, 8)
    K2NCHUNK(5, vA, vB, 1, 1, 8)
    K2NCHUNK(6, vB, vA, 1, 0, 0)
    {   // chunk 7: A-frags + MFMA only (X_7 already in sX[1], Wt_7 in sWt)
        int row0 = w * 32 + l15, row1 = w * 32 + 16 + l15;
        u16x8 af0 = *(const u16x8*)&sWt[row0 * 64 + (((0 + l4) ^ (row0 & 7)) << 3)];
        u16x8 af1 = *(const u16x8*)&sWt[row1 * 64 + (((0 + l4) ^ (row1 & 7)) << 3)];
        u16x8 af2 = *(const u16x8*)&sWt[row0 * 64 + (((4 + l4) ^ (row0 & 7)) << 3)];
        u16x8 af3 = *(const u16x8*)&sWt[row1 * 64 + (((4 + l4) ^ (row1 & 7)) << 3)];
#pragma unroll
        for (int kk = 0; kk < 2; kk++) {
            u16x8 bf[4];
#pragma unroll
            for (int ht = 0; ht < 4; ht++) {
                int row = ht * 16 + l15;
                bf[ht] = *(const u16x8*)&sX[4096 + row * 64 + (((kk*4+l4) ^ (row&7)) << 3)];
            }
#pragma unroll
            for (int ht = 0; ht < 4; ht++) {
                acc[0][ht] = mfma16(kk == 0 ? af0 : af2, bf[ht], acc[0][ht]);
                acc[1][ht] = mfma16(kk == 0 ? af1 : af3, bf[ht], acc[1][ht]);
            }
        }
    }

    // poly: xx = c1*t + c2*t^2
#pragma unroll
    for (int i = 0; i < 2; i++)
#pragma unroll
        for (int ht = 0; ht < 4; ht++) {
            f32x4 t = acc[i][ht];
            acc[i][ht] = c1v * t + c2v * t * t;
        }
    __syncthreads();   // reuse sWt as xx, sX as sR

    // xx -> sWt as [64 hw][256 p] bf16; wave granules [4w,4w+4), swz ^(row&3)
#pragma unroll
    for (int i = 0; i < 2; i++)
#pragma unroll
        for (int ht = 0; ht < 4; ht++) {
            int row = ht * 16 + l15;
            f32x4 xv = acc[i][ht];
            uint2 q = { cvtpk(xv[0], xv[1]), cvtpk(xv[2], xv[3]) };
            int phys = w * 4 + ((i * 2 + (l4 >> 1)) ^ (row & 3));
            *(uint2*)&sWt[row * 256 + phys * 8 + (l4 & 1) * 4] = q;
        }

    float* sR = (float*)sX;
    {
        const float* wr = Wz + (size_t)tid * 32;
        float s = 0.f;
#pragma unroll
        for (int q = 0; q < 8; q++) {
            float4 v = ((const float4*)wr)[q];
            s += v.x + v.y + v.z + v.w;
        }
        sR[tid] = s;
    }
    u16x8 wzf[4];
#pragma unroll
    for (int ot = 0; ot < 4; ot++) {
        const float* wr = Wz + (size_t)(w * 64 + ot * 16 + l15) * 32 + l4 * 8;
        float4 v0 = ((const float4*)wr)[0];
        float4 v1 = ((const float4*)wr)[1];
        uint4 q = { cvtpk(v0.x,v0.y), cvtpk(v0.z,v0.w),
                    cvtpk(v1.x,v1.y), cvtpk(v1.z,v1.w) };
        wzf[ot] = *(u16x8*)&q;
    }
    __syncthreads();

    float s = 0.f, s2a = 0.f;
    f32x4 zero4 = {0.f, 0.f, 0.f, 0.f};
#pragma unroll
    for (int ht = 0; ht < 4; ht++) {
        int row = ht * 16 + l15;
        u16x8 bfr = *(const u16x8*)&sWt[row * 256 + (w * 4 + (l4 ^ (row & 3))) * 8];
#pragma unroll
        for (int ot = 0; ot < 4; ot++) {
            f32x4 z = mfma16(wzf[ot], bfr, zero4);
            f32x4 rv = *(const f32x4*)&sR[w * 64 + ot * 16 + l4 * 4];
            z = z + c0v * rv;
            float* zp = zout + ((size_t)(b * 512 + w * 64 + ot * 16 + l4 * 4)) * 4096
                      + hw0 + ht * 16 + l15;
#pragma unroll
            for (int r = 0; r < 4; r++) {
                zp[(size_t)r * 4096] = z[r];
                s += z[r]; s2a += z[r] * z[r];
            }
        }
    }
#pragma unroll
    for (int m = 1; m < 64; m <<= 1) {
        s   += __shfl_xor(s, m);
        s2a += __shfl_xor(s2a, m);
    }
    if (lane == 0) {
        atomicAdd(&zstat[(size_t)(b * 8 + w) * 2 + 0], s);
        atomicAdd(&zstat[(size_t)(b * 8 + w) * 2 + 1], s2a);
    }
}

// ---------------------------------------------------------------------------
// k2 fallback (fp32 Wt staging) when ws too small for wtb.
// ---------------------------------------------------------------------------
#define K2_BODY(C0, VCUR, VNXT, DOPREF)                                          \
  {                                                                              \
    if (DOPREF) {                                                                \
        const float* xc = xhi + ((size_t)b * 512 + (C0) + 64 + w * 8) * 4096 + hw0 + xrow; \
        _Pragma("unroll")                                                        \
        for (int j = 0; j < 8; j++) VNXT[j] = xc[(size_t)j * 4096];              \
    }                                                                            \
    __syncthreads();                                                             \
    _Pragma("unroll")                                                            \
    for (int k = 0; k < 4; k++) {                                                \
        int idx = k * 512 + tid;                                                 \
        int row = idx >> 3, s = idx & 7;                                         \
        const float* sp = Wt + (size_t)row * 512 + (C0) + s * 8;                 \
        float4 v0 = ((const float4*)sp)[0];                                      \
        float4 v1 = ((const float4*)sp)[1];                                      \
        uint4 q = { cvtpk(v0.x,v0.y), cvtpk(v0.z,v0.w),                          \
                    cvtpk(v1.x,v1.y), cvtpk(v1.z,v1.w) };                        \
        *(uint4*)&sWt[row * 64 + ((s ^ (row & 7)) << 3)] = q;                    \
    }                                                                            \
    {                                                                            \
        uint4 q = { cvtpk(VCUR[0],VCUR[1]), cvtpk(VCUR[2],VCUR[3]),              \
                    cvtpk(VCUR[4],VCUR[5]), cvtpk(VCUR[6],VCUR[7]) };            \
        int phys = w ^ (xrow & 7);                                               \
        *(uint4*)&sX[xrow * 64 + phys * 8] = q;                                  \
    }                                                                            \
    __syncthreads();                                                             \
    _Pragma("unroll")                                                            \
    for (int kk = 0; kk < 2; kk++) {                                             \
        u16x8 bf[4];                                                             \
        _Pragma("unroll")                                                        \
        for (int ht = 0; ht < 4; ht++) {                                         \
            int row = ht * 16 + l15;                                             \
            bf[ht] = *(const u16x8*)&sX[row * 64 + (((kk*4+l4) ^ (row&7)) << 3)]; \
        }                                                                        \
        _Pragma("unroll")                                                        \
        for (int i = 0; i < 2; i++) {                                            \
            int row = w * 32 + i * 16 + l15;                                     \
            u16x8 af = *(const u16x8*)&sWt[row * 64 + (((kk*4+l4) ^ (row&7)) << 3)]; \
            _Pragma("unroll")                                                    \
            for (int ht = 0; ht < 4; ht++)                                       \
                acc[i][ht] = mfma16(af, bf[ht], acc[i][ht]);                     \
        }                                                                        \
    }                                                                            \
  }

__global__ __launch_bounds__(512, 4)
void k2_main_fb(const float* __restrict__ xhi, const float* __restrict__ Wt,
                const float* __restrict__ Wz, const float* __restrict__ coef,
                float* __restrict__ zout, float* __restrict__ zstat)
{
    __shared__ unsigned short sWt[16384];
    __shared__ unsigned short sX[8192];

    int tid = threadIdx.x;
    int w = tid >> 6, lane = tid & 63;
    int l15 = lane & 15, l4 = lane >> 4;
    int hwt = blockIdx.x & 63, b = blockIdx.x >> 6;
    int hw0 = hwt * 64;
    int xrow = tid & 63;

    const float* cf = coef + (size_t)(b * 8 + w) * 3;
    float c0v = cf[0], c1v = cf[1], c2v = cf[2];

    f32x4 acc[2][4] = {};

    float vbA[8], vbB[8];
    {
        const float* xc = xhi + ((size_t)b * 512 + w * 8) * 4096 + hw0 + xrow;
#pragma unroll
        for (int j = 0; j < 8; j++) vbA[j] = xc[(size_t)j * 4096];
    }

    for (int kc2 = 0; kc2 < 4; kc2++) {
        int c0 = kc2 * 128;
        K2_BODY(c0,      vbA, vbB, true);
        K2_BODY(c0 + 64, vbB, vbA, (kc2 < 3));
    }

#pragma unroll
    for (int i = 0; i < 2; i++)
#pragma unroll
        for (int ht = 0; ht < 4; ht++) {
            f32x4 t = acc[i][ht];
            acc[i][ht] = c1v * t + c2v * t * t;
        }
    __syncthreads();
#pragma unroll
    for (int i = 0; i < 2; i++)
#pragma unroll
        for (int ht = 0; ht < 4; ht++) {
            int row = ht * 16 + l15;
            f32x4 xv = acc[i][ht];
            uint2 q = { cvtpk(xv[0], xv[1]), cvtpk(xv[2], xv[3]) };
            int phys = w * 4 + ((i * 2 + (l4 >> 1)) ^ (row & 3));
            *(uint2*)&sWt[row * 256 + phys * 8 + (l4 & 1) * 4] = q;
        }
    float* sR = (float*)sX;
    {
        const float* wr = Wz + (size_t)tid * 32;
        float s = 0.f;
#pragma unroll
        for (int q = 0; q < 8; q++) {
            float4 v = ((const float4*)wr)[q];
            s += v.x + v.y + v.z + v.w;
        }
        sR[tid] = s;
    }
    u16x8 wzf[4];
#pragma unroll
    for (int ot = 0; ot < 4; ot++) {
        const float* wr = Wz + (size_t)(w * 64 + ot * 16 + l15) * 32 + l4 * 8;
        float4 v0 = ((const float4*)wr)[0];
        float4 v1 = ((const float4*)wr)[1];
        uint4 q = { cvtpk(v0.x,v0.y), cvtpk(v0.z,v0.w),
                    cvtpk(v1.x,v1.y), cvtpk(v1.z,v1.w) };
        wzf[ot] = *(u16x8*)&q;
    }
    __syncthreads();

    float s = 0.f, s2a = 0.f;
    f32x4 zero4 = {0.f, 0.f, 0.f, 0.f};
#pragma unroll
    for (int ht = 0; ht < 4; ht++) {
        int row = ht * 16 + l15;
        u16x8 bfr = *(const u16x8*)&sWt[row * 256 + (w * 4 + (l4 ^ (row & 3))) * 8];
#pragma unroll
        for (int ot = 0; ot < 4; ot++) {
            f32x4 z = mfma16(wzf[ot], bfr, zero4);
            f32x4 rv = *(const f32x4*)&sR[w * 64 + ot * 16 + l4 * 4];
            z = z + c0v * rv;
            float* zp = zout + ((size_t)(b * 512 + w * 64 + ot * 16 + l4 * 4)) * 4096
                      + hw0 + ht * 16 + l15;
#pragma unroll
            for (int r = 0; r < 4; r++) {
                zp[(size_t)r * 4096] = z[r];
                s += z[r]; s2a += z[r] * z[r];
            }
        }
    }
#pragma unroll
    for (int m = 1; m < 64; m <<= 1) {
        s   += __shfl_xor(s, m);
        s2a += __shfl_xor(s2a, m);
    }
    if (lane == 0) {
        atomicAdd(&zstat[(size_t)(b * 8 + w) * 2 + 0], s);
        atomicAdd(&zstat[(size_t)(b * 8 + w) * 2 + 1], s2a);
    }
}

__global__ void k2b_gn(const float* __restrict__ zstat, float* __restrict__ gnstat)
{
    int t = threadIdx.x;
    if (t >= 128) return;
    float S = zstat[t * 2], S2 = zstat[t * 2 + 1];
    const float N = 64.0f * 4096.0f;
    float mean = S / N;
    float var = S2 / N - mean * mean;
    var = var < 0.f ? 0.f : var;
    gnstat[t * 2] = mean;
    gnstat[t * 2 + 1] = rsqrtf(var + EPS_);
}

// ---------------------------------------------------------------------------
// k3: out = (z - mean)*rsig*gn_w + gn_b + input_high  (in place on d_out)
// ---------------------------------------------------------------------------
__global__ __launch_bounds__(256)
void k3_final(float* __restrict__ out, const float* __restrict__ xhi,
              const float* __restrict__ gnstat, const float* __restrict__ gnw,
              const float* __restrict__ gnb)
{
#pragma unroll
    for (int k = 0; k < 4; k++) {
        size_t idx = (size_t)blockIdx.x * 1024 + (size_t)k * 256 + threadIdx.x;
        size_t e = idx * 4;
        int ch = (int)((e >> 12) & 511);
        int b  = (int)(e >> 21);
        int gg = ch >> 6;
        const float* gs = gnstat + (size_t)(b * 8 + gg) * 2;
        float mean = gs[0];
        float w = gnw[ch] * gs[1];
        float bb = gnb[ch];
        float4 z = ((const float4*)out)[idx];
        float4 xv = ((const float4*)xhi)[idx];
        float4 r;
        r.x = (z.x - mean) * w + bb + xv.x;
        r.y = (z.y - mean) * w + bb + xv.y;
        r.z = (z.z - mean) * w + bb + xv.z;
        r.w = (z.w - mean) * w + bb + xv.w;
        ((float4*)out)[idx] = r;
    }
}

extern "C" void kernel_launch(void* const* d_in, const int* in_sizes, int n_in,
                              void* d_out, int out_size, void* d_ws, size_t ws_size,
                              hipStream_t stream) {
    (void)in_sizes; (void)n_in; (void)out_size;
    const float* xhi = (const float*)d_in[0];
    const float* xlo = (const float*)d_in[1];
    const float* Wt  = (const float*)d_in[2];
    const float* Wp  = (const float*)d_in[3];
    const float* Wg  = (const float*)d_in[4];
    const float* Wz  = (const float*)d_in[5];
    const float* gnw = (const float*)d_in[6];
    const float* gnb = (const float*)d_in[7];
    float* out = (float*)d_out;
    float* ws  = (float*)d_ws;

    float* sxsum    = ws;              // 8192 floats
    float* att_part = ws + 8192;       // 8192
    float* coef     = ws + 16384;      // 384
    float* zstat    = ws + 16768;      // 256
    float* gnstat   = ws + 17024;      // 256   -> 17280 f = 69120 B
    unsigned short* wtb = (unsigned short*)((char*)d_ws + 69632);  // 262144 B

    const size_t WS_NEED = 69632 + 262144;   // 331776
    bool use_gll = (ws_size >= WS_NEED);

    double g2 = 2.0e-4;
    double ee = exp(-g2);
    float a0s = (float)ee;
    float a1s = (float)(g2 * ee);
    float a2s = (float)(g2 * g2 * 0.5 * ee);

    k0s     <<<dim3(256),  dim3(256), 0, stream>>>(xlo, sxsum);
    k1_att  <<<dim3(1024), dim3(256), 0, stream>>>(xlo, Wp, Wg, att_part);
    k1b_coef<<<dim3(128),  dim3(64),  0, stream>>>(Wg, sxsum, att_part, coef, a0s, a1s, a2s);
    hipMemsetAsync(zstat, 0, 256 * sizeof(float), stream);
    if (use_gll) {
        k0w_t    <<<dim3(64),   dim3(256), 0, stream>>>(Wt, wtb);
        k2_main_g<<<dim3(1024), dim3(512), 0, stream>>>(xhi, wtb, Wz, coef, out, zstat);
    } else {
        k2_main_fb<<<dim3(1024), dim3(512), 0, stream>>>(xhi, Wt, Wz, coef, out, zstat);
    }
    k2b_gn  <<<dim3(1),    dim3(128), 0, stream>>>(zstat, gnstat);
    k3_final<<<dim3(8192), dim3(256), 0, stream>>>(out, xhi, gnstat, gnw, gnb);
}